// Round 9
// baseline (317.239 us; speedup 1.0000x reference)
//
#include <hip/hip_runtime.h>
#include <hip/hip_bf16.h>

#define BB 4
#define LL 2048
#define DD 512
#define DKK 256

typedef __bf16 bf16;
typedef __bf16 bf16x4 __attribute__((ext_vector_type(4)));
typedef __bf16 bf16x8 __attribute__((ext_vector_type(8)));
typedef float f32x4 __attribute__((ext_vector_type(4)));

__device__ __forceinline__ void async_ld16(const bf16* g, bf16* l) {
    __builtin_amdgcn_global_load_lds(
        (const __attribute__((address_space(1))) void*)g,
        (__attribute__((address_space(3))) void*)l, 16, 0, 0);
}

// One fused f32->bf16 conversion pass for inQ, inK, inV, E.
__global__ void conv_all(const float* __restrict__ q, const float* __restrict__ k,
                         const float* __restrict__ v, const float* __restrict__ e,
                         bf16* __restrict__ xq, bf16* __restrict__ xk,
                         bf16* __restrict__ xv, bf16* __restrict__ eb) {
    const int NV = (BB * LL * DD) / 4;
    const int NE = (LL * DKK) / 4;
    int i = blockIdx.x * 256 + threadIdx.x;
    const float* src; bf16* dst; int idx;
    if      (i < NV)          { src = q; dst = xq; idx = i; }
    else if (i < 2 * NV)      { src = k; dst = xk; idx = i - NV; }
    else if (i < 3 * NV)      { src = v; dst = xv; idx = i - 2 * NV; }
    else if (i < 3 * NV + NE) { src = e; dst = eb; idx = i - 3 * NV; }
    else return;
    f32x4 val = *(const f32x4*)(src + (size_t)idx * 4);
    bf16x4 o;
    #pragma unroll
    for (int j = 0; j < 4; ++j) o[j] = (bf16)val[j];
    *(bf16x4*)(dst + (size_t)idx * 4) = o;
}

__global__ void transpose_f32_bf16(const float* __restrict__ in, bf16* __restrict__ out,
                                   int R, int C) {
    int idx = blockIdx.x * 256 + threadIdx.x;
    if (idx < R * C) {
        int r = idx / C, c = idx % C;
        out[(size_t)c * R + r] = (bf16)in[idx];
    }
}

// 64x64-tile bf16 transpose: in [R][C] -> out [C][R], coalesced both sides.
__global__ void transpose_bf16_tile(const bf16* __restrict__ in, bf16* __restrict__ out,
                                    int R, int C) {
    __shared__ bf16 t[64][72];
    int tcx = C >> 6;
    int bx = blockIdx.x % tcx, by = blockIdx.x / tcx;
    int r = threadIdx.x >> 2, cc = (threadIdx.x & 3) * 16;
    const bf16* src = in + (size_t)(by * 64 + r) * C + bx * 64 + cc;
    bf16x8 v0 = *(const bf16x8*)src;
    bf16x8 v1 = *(const bf16x8*)(src + 8);
    #pragma unroll
    for (int u = 0; u < 8; ++u) { t[cc + u][r] = v0[u]; t[cc + 8 + u][r] = v1[u]; }
    __syncthreads();
    bf16* dst = out + (size_t)(bx * 64 + r) * R + by * 64 + cc;
    *(bf16x8*)dst = *(const bf16x8*)&t[r][cc];
    *(bf16x8*)(dst + 8) = *(const bf16x8*)&t[r][cc + 8];
}

// 128x128-tile bf16 GEMM: C[m][n] = sum_k A[m][k]*B[n][k].  4 waves (64x64 each).
// A/B staged via global_load_lds(16B), parity-rotation swizzle.
// blockIdx.y indexes a batch with strides for A/B/C (lets Q+K proj share one dispatch).
template <int SKEW>
__launch_bounds__(256, 2)
__global__ void gemm128(const bf16* __restrict__ A, const bf16* __restrict__ B,
                        bf16* __restrict__ C, int N, int K,
                        long aStride, long bStride, long cStride)
{
    __shared__ bf16 Als[128 * 32];
    __shared__ bf16 Bls[128 * 32];

    int tid  = threadIdx.x;
    int lane = tid & 63;
    int wid  = tid >> 6;
    int l15  = lane & 15;
    int quad = lane >> 4;
    int nb = N >> 7;
    int gx = blockIdx.x % nb;
    int gy = blockIdx.x / nb;

    const bf16* Ab = A + (size_t)blockIdx.y * aStride + (size_t)gy * 128 * K;
    const bf16* Bb = B + (size_t)blockIdx.y * bStride + (size_t)gx * 128 * K;

    int rl = lane >> 2;
    int sl = lane & 3;
    int half = wid & 1;
    const bf16* gsrc = (wid < 2) ? Ab : Bb;
    bf16* ldst = (wid < 2) ? Als : Bls;

    f32x4 acc[4][4];
    #pragma unroll
    for (int i = 0; i < 4; ++i)
        #pragma unroll
        for (int j = 0; j < 4; ++j) acc[i][j] = 0;

    for (int k0 = 0; k0 < K; k0 += 32) {
        #pragma unroll
        for (int u = 0; u < 4; ++u) {
            int inst = half * 4 + u;
            int row  = inst * 16 + rl;
            int c    = (sl - (row >> 1)) & 3;
            async_ld16(gsrc + (size_t)row * K + k0 + c * 8, ldst + inst * 512);
        }
        __syncthreads();
        bf16x8 fA[4], fB[4];
        #pragma unroll
        for (int rt = 0; rt < 4; ++rt) {
            int row = (wid & 1) * 64 + rt * 16 + l15;
            int s   = (quad + (row >> 1)) & 3;
            fA[rt] = *(const bf16x8*)&Als[row * 32 + s * 8];
        }
        #pragma unroll
        for (int ct = 0; ct < 4; ++ct) {
            int col = (wid >> 1) * 64 + ct * 16 + l15;
            int s   = (quad + (col >> 1)) & 3;
            fB[ct] = *(const bf16x8*)&Bls[col * 32 + s * 8];
        }
        #pragma unroll
        for (int rt = 0; rt < 4; ++rt)
            #pragma unroll
            for (int ct = 0; ct < 4; ++ct)
                acc[rt][ct] = __builtin_amdgcn_mfma_f32_16x16x32_bf16(
                                  fA[rt], fB[ct], acc[rt][ct], 0, 0, 0);
        __syncthreads();
    }

    bf16* Cb = C + (size_t)blockIdx.y * cStride;
    int m0 = gy * 128 + (wid & 1) * 64;
    int n0 = gx * 128 + (wid >> 1) * 64;
    if (!SKEW) {
        #pragma unroll
        for (int rt = 0; rt < 4; ++rt)
            #pragma unroll
            for (int ct = 0; ct < 4; ++ct)
                #pragma unroll
                for (int r = 0; r < 4; ++r) {
                    int m = m0 + rt * 16 + quad * 4 + r;
                    int n = n0 + ct * 16 + l15;
                    Cb[(size_t)m * N + n] = (bf16)acc[rt][ct][r];
                }
    } else {
        // scatter into skewed Srel: QE[r][c] -> (c>=L-1-r) ? S[r][c-(L-1-r)]
        //                                       : (r>=1 ? S[r-1][c+r+1] : drop)
        #pragma unroll
        for (int rt = 0; rt < 4; ++rt)
            #pragma unroll
            for (int ct = 0; ct < 4; ++ct)
                #pragma unroll
                for (int r = 0; r < 4; ++r) {
                    int row = m0 + rt * 16 + quad * 4 + r;
                    int c   = n0 + ct * 16 + l15;
                    bool lower = (c >= LL - 1 - row);
                    int dr = lower ? row : row - 1;
                    int dc = lower ? c - (LL - 1 - row) : c + row + 1;
                    if (lower || row >= 1)
                        Cb[(size_t)dr * LL + dc] = (bf16)acc[rt][ct][r];
                }
    }
}

// Fused attention v5: XCD-pinned (blockIdx%8 -> (b,dh)); K staged to LDS async;
// V read DIRECT global->VGPR (per-wave-private data, XCD-L2-resident after R7
// pinning — no reason to round-trip LDS); 3 barriers/iter (b4 dropped: K WAR
// protected by b2+b3, Ps WAR by b1'+b2'); LDS 46.5 KB -> 3 blocks/CU.
// All accO loops fully unrolled (R3: dynamic index => scratch spill).
__launch_bounds__(256, 3)
__global__ void attn_kernel(const bf16* __restrict__ Qw, const bf16* __restrict__ Kw,
                            const bf16* __restrict__ Vt, const bf16* __restrict__ Srel,
                            float* __restrict__ out)
{
    __shared__ bf16  Klds[64 * 256];
    __shared__ float Ss[32][68];
    __shared__ bf16  Ps[32][72];
    __shared__ float mSt[32], lSt[32], aSt[32];

    int tid  = threadIdx.x;
    int lane = tid & 63;
    int wid  = tid >> 6;
    int l15  = lane & 15;
    int quad = lane >> 4;

    int xcd = blockIdx.x & 7;
    int b   = xcd >> 1;
    int dh  = xcd & 1;
    int i0  = (blockIdx.x >> 3) * 32;

    const bf16* Qb = Qw + (size_t)b * LL * DKK;
    const bf16* Kb = Kw + (size_t)b * LL * DKK;
    const bf16* Sb = Srel + (size_t)b * LL * LL;
    const bf16* Vb = Vt + (size_t)(dh * 256) * (BB * LL) + (size_t)b * LL;

    bf16x8 Qreg[2][8];
    #pragma unroll
    for (int rt = 0; rt < 2; ++rt)
        #pragma unroll
        for (int ks = 0; ks < 8; ++ks)
            Qreg[rt][ks] = *(const bf16x8*)(Qb + (size_t)(i0 + rt * 16 + l15) * DKK
                                            + ks * 32 + quad * 8);

    if (tid < 32) { mSt[tid] = -1e30f; lSt[tid] = 0.f; }

    f32x4 accO[2][4];
    #pragma unroll
    for (int rt = 0; rt < 2; ++rt)
        #pragma unroll
        for (int nt = 0; nt < 4; ++nt) accO[rt][nt] = 0;

    for (int j0 = 0; j0 < LL; j0 += 64) {
        // ---- stage K tile [64 j][256 k] async to LDS (rotated chunks)
        #pragma unroll
        for (int u = 0; u < 8; ++u) {
            int inst = wid * 8 + u;
            int s = inst * 64 + lane;
            int j = s >> 5, cp = lane & 31;
            int c = (cp - j) & 31;
            async_ld16(Kb + (size_t)(j0 + j) * DKK + c * 8, Klds + inst * 512);
        }
        // ---- V fragments direct to VGPR (L2-local; drains with staging at b1)
        bf16x8 vF0[4], vF1[4];
        #pragma unroll
        for (int nt = 0; nt < 4; ++nt) {
            const bf16* vp = Vb + (size_t)(wid * 64 + nt * 16 + l15) * (BB * LL)
                           + j0 + quad * 8;
            vF0[nt] = *(const bf16x8*)(vp);
            vF1[nt] = *(const bf16x8*)(vp + 32);
        }
        __syncthreads();                                    // b1
        // ---- S = Q·K^T : wave owns 16-col strip, both row-tiles
        {
            f32x4 s0 = 0, s1 = 0;
            int jrow = wid * 16 + l15;
            #pragma unroll
            for (int ks = 0; ks < 8; ++ks) {
                int c = ks * 4 + quad;
                int cp = (c + jrow) & 31;
                bf16x8 kf = *(const bf16x8*)&Klds[jrow * 256 + cp * 8];
                s0 = __builtin_amdgcn_mfma_f32_16x16x32_bf16(Qreg[0][ks], kf, s0, 0, 0, 0);
                s1 = __builtin_amdgcn_mfma_f32_16x16x32_bf16(Qreg[1][ks], kf, s1, 0, 0, 0);
            }
            #pragma unroll
            for (int r = 0; r < 4; ++r) {
                Ss[quad * 4 + r][wid * 16 + l15]      = s0[r];
                Ss[16 + quad * 4 + r][wid * 16 + l15] = s1[r];
            }
        }
        __syncthreads();                                    // b2
        // ---- online softmax (8 threads/row) with coalesced Srel add
        {
            int r = tid >> 3, sg = tid & 7;
            int i = i0 + r;
            bf16x8 s8 = *(const bf16x8*)(Sb + (size_t)i * LL + j0 + sg * 8);
            float v[8];
            #pragma unroll
            for (int c = 0; c < 8; ++c) {
                float sr = (j0 + sg * 8 + c == i + 1) ? 0.f : (float)s8[c];
                v[c] = (Ss[r][sg * 8 + c] + sr) * 0.0625f;
            }
            float tmax = v[0];
            #pragma unroll
            for (int c = 1; c < 8; ++c) tmax = fmaxf(tmax, v[c]);
            tmax = fmaxf(tmax, __shfl_xor(tmax, 1));
            tmax = fmaxf(tmax, __shfl_xor(tmax, 2));
            tmax = fmaxf(tmax, __shfl_xor(tmax, 4));
            float mOld = mSt[r], lOld = lSt[r];
            float mNew = fmaxf(mOld, tmax);
            float alpha = __expf(mOld - mNew);
            float ps = 0.f;
            bf16x8 pv;
            #pragma unroll
            for (int c = 0; c < 8; ++c) {
                float p = __expf(v[c] - mNew);
                ps += p;
                pv[c] = (bf16)p;
            }
            ps += __shfl_xor(ps, 1);
            ps += __shfl_xor(ps, 2);
            ps += __shfl_xor(ps, 4);
            *(bf16x8*)&Ps[r][sg * 8] = pv;
            if (sg == 0) { mSt[r] = mNew; lSt[r] = alpha * lOld + ps; aSt[r] = alpha; }
        }
        __syncthreads();                                    // b3
        // ---- O = alpha*O + P·V (V already in VGPRs)
        {
            bf16x8 aF[2][2];
            #pragma unroll
            for (int rt = 0; rt < 2; ++rt)
                #pragma unroll
                for (int kk = 0; kk < 2; ++kk)
                    aF[rt][kk] = *(const bf16x8*)&Ps[rt * 16 + l15][kk * 32 + quad * 8];
            float ar[2][4];
            #pragma unroll
            for (int rt = 0; rt < 2; ++rt)
                #pragma unroll
                for (int r = 0; r < 4; ++r) ar[rt][r] = aSt[rt * 16 + quad * 4 + r];
            #pragma unroll
            for (int nt = 0; nt < 4; ++nt) {
                #pragma unroll
                for (int rt = 0; rt < 2; ++rt) {
                    f32x4 o = accO[rt][nt];
                    o[0] *= ar[rt][0]; o[1] *= ar[rt][1];
                    o[2] *= ar[rt][2]; o[3] *= ar[rt][3];
                    o = __builtin_amdgcn_mfma_f32_16x16x32_bf16(aF[rt][0], vF0[nt], o, 0, 0, 0);
                    o = __builtin_amdgcn_mfma_f32_16x16x32_bf16(aF[rt][1], vF1[nt], o, 0, 0, 0);
                    accO[rt][nt] = o;
                }
            }
        }
        // (no b4: next-iter Klds writes WAR-protected by b2+b3; Ps by b1'+b2')
    }
    float lr[2][4];
    #pragma unroll
    for (int rt = 0; rt < 2; ++rt)
        #pragma unroll
        for (int r = 0; r < 4; ++r) lr[rt][r] = 1.f / lSt[rt * 16 + quad * 4 + r];
    #pragma unroll
    for (int rt = 0; rt < 2; ++rt)
        #pragma unroll
        for (int nt = 0; nt < 4; ++nt)
            #pragma unroll
            for (int r = 0; r < 4; ++r) {
                int i = i0 + rt * 16 + quad * 4 + r;
                int d = dh * 256 + wid * 64 + nt * 16 + l15;
                out[((size_t)b * LL + i) * DD + d] = accO[rt][nt][r] * lr[rt][r];
            }
}

extern "C" void kernel_launch(void* const* d_in, const int* in_sizes, int n_in,
                              void* d_out, int out_size, void* d_ws, size_t ws_size,
                              hipStream_t stream) {
    const float* inQ = (const float*)d_in[0];
    const float* inK = (const float*)d_in[1];
    const float* inV = (const float*)d_in[2];
    const float* Wq  = (const float*)d_in[3];
    const float* Wk  = (const float*)d_in[4];
    const float* Wv  = (const float*)d_in[5];
    const float* E   = (const float*)d_in[6];
    float* out = (float*)d_out;

    char* ws = (char*)d_ws;
    bf16* Qw   = (bf16*)(ws);                         // 4 MB [B*L][DK]   (Kw = +4MB)
    bf16* Kw   = (bf16*)(ws + ((size_t)4  << 20));    // 4 MB [B*L][DK]
    bf16* Vt   = (bf16*)(ws + ((size_t)8  << 20));    // 8 MB [D][B*L]
    bf16* SrelW= (bf16*)(ws + ((size_t)16 << 20));    // 32 MB [B,L,L] skewed
    // transients inside Srel region (dead before Srel gemm writes):
    bf16* Xq   = (bf16*)(ws + ((size_t)16 << 20));    // 8 MB  (Xk = +8MB)
    bf16* Xk   = (bf16*)(ws + ((size_t)24 << 20));    // 8 MB
    bf16* Xv   = (bf16*)(ws + ((size_t)32 << 20));    // 8 MB
    bf16* Vw   = (bf16*)(ws + ((size_t)40 << 20));    // 8 MB  V row-major
    bf16* WqT  = (bf16*)(ws + ((size_t)48 << 20));              // [DK][D] (WkT = +256KB)
    bf16* WkT  = (bf16*)(ws + ((size_t)48 << 20) + 262144);
    bf16* WvT  = (bf16*)(ws + ((size_t)48 << 20) + 524288);     // [D][D]
    bf16* Eb   = (bf16*)(ws + ((size_t)49 << 20));              // [L][DK]

    {   // all f32->bf16 conversions in one dispatch
        const int NV = (BB * LL * DD) / 4, NE = (LL * DKK) / 4;
        conv_all<<<(3 * NV + NE + 255) / 256, 256, 0, stream>>>(
            inQ, inK, inV, E, Xq, Xk, Xv, Eb);
    }
    transpose_f32_bf16<<<512,  256, 0, stream>>>(Wq, WqT, DD, DKK);
    transpose_f32_bf16<<<512,  256, 0, stream>>>(Wk, WkT, DD, DKK);
    transpose_f32_bf16<<<1024, 256, 0, stream>>>(Wv, WvT, DD, DD);

    // Q and K projections fused: y=0 -> Q, y=1 -> K (buffer-offset strides).
    gemm128<0><<<dim3(2 * 64, 2), 256, 0, stream>>>(
        Xq, WqT, Qw, DKK, DD,
        (long)4 * 1024 * 1024,      // Xk - Xq (elems)
        (long)131072,               // WkT - WqT
        (long)2 * 1024 * 1024);     // Kw - Qw
    // V projection: M=8192 N=512 K=512
    gemm128<0><<<dim3(4 * 64, 1), 256, 0, stream>>>(Xv, WvT, Vw, DD, DD, 0, 0, 0);
    // Vt = Vw^T
    transpose_bf16_tile<<<(DD / 64) * (BB * LL / 64), 256, 0, stream>>>(Vw, Vt, BB * LL, DD);
    // Srel (skewed) = skew(Q·E^T): per-batch M=N=2048 K=256
    gemm128<1><<<dim3(16 * 16, BB), 256, 0, stream>>>(Qw, Eb, SrelW, LL, DKK,
                                                      (long)LL * DKK, 0, (long)LL * LL);
    attn_kernel<<<dim3(BB * 64 * 2), 256, 0, stream>>>(Qw, Kw, Vt, SrelW, out);
}

// Round 10
// 272.629 us; speedup vs baseline: 1.1636x; 1.1636x over previous
//
#include <hip/hip_runtime.h>
#include <hip/hip_bf16.h>

#define BB 4
#define LL 2048
#define DD 512
#define DKK 256

typedef __bf16 bf16;
typedef __bf16 bf16x4 __attribute__((ext_vector_type(4)));
typedef __bf16 bf16x8 __attribute__((ext_vector_type(8)));
typedef float f32x4 __attribute__((ext_vector_type(4)));

__device__ __forceinline__ void async_ld16(const bf16* g, bf16* l) {
    __builtin_amdgcn_global_load_lds(
        (const __attribute__((address_space(1))) void*)g,
        (__attribute__((address_space(3))) void*)l, 16, 0, 0);
}

// One fused f32->bf16 conversion pass for inQ, inK, inV, E.
__global__ void conv_all(const float* __restrict__ q, const float* __restrict__ k,
                         const float* __restrict__ v, const float* __restrict__ e,
                         bf16* __restrict__ xq, bf16* __restrict__ xk,
                         bf16* __restrict__ xv, bf16* __restrict__ eb) {
    const int NV = (BB * LL * DD) / 4;
    const int NE = (LL * DKK) / 4;
    int i = blockIdx.x * 256 + threadIdx.x;
    const float* src; bf16* dst; int idx;
    if      (i < NV)          { src = q; dst = xq; idx = i; }
    else if (i < 2 * NV)      { src = k; dst = xk; idx = i - NV; }
    else if (i < 3 * NV)      { src = v; dst = xv; idx = i - 2 * NV; }
    else if (i < 3 * NV + NE) { src = e; dst = eb; idx = i - 3 * NV; }
    else return;
    f32x4 val = *(const f32x4*)(src + (size_t)idx * 4);
    bf16x4 o;
    #pragma unroll
    for (int j = 0; j < 4; ++j) o[j] = (bf16)val[j];
    *(bf16x4*)(dst + (size_t)idx * 4) = o;
}

// All three weight transposes (f32 [R][C] -> bf16 [C][R]) in one dispatch.
__global__ void trans_all(const float* __restrict__ wq, const float* __restrict__ wk,
                          const float* __restrict__ wv,
                          bf16* __restrict__ tq, bf16* __restrict__ tk,
                          bf16* __restrict__ tv) {
    const int N1 = DD * DKK, N3 = DD * DD;
    int i = blockIdx.x * 256 + threadIdx.x;
    const float* src; bf16* dst; int idx, C;
    if      (i < N1)          { src = wq; dst = tq; idx = i;          C = DKK; }
    else if (i < 2 * N1)      { src = wk; dst = tk; idx = i - N1;     C = DKK; }
    else if (i < 2 * N1 + N3) { src = wv; dst = tv; idx = i - 2 * N1; C = DD;  }
    else return;
    int r = idx / C, c = idx % C;
    int R = (C == DKK) ? DD : DD;
    dst[(size_t)c * R + r] = (bf16)src[idx];
}

// 128x128-tile bf16 GEMM, BK=64: C[m][n] = sum_k A[m][k]*B[n][k].  4 waves.
// A/B staged via global_load_lds(16B), rotation swizzle (slot=(c+row)&7, pitch
// 128B -> 2 lanes/bank on frag reads = free).  32 MFMA per barrier-pair.
// TRANS=1: C^T stored via 32KB smem tile reuse (d-major for attn's Vt).
// SKEW=1: scatter into skewed Srel: QE[r][c] -> (c>=L-1-r) ? S[r][c-(L-1-r)]
//         : (r>=1 ? S[r-1][c+r+1] : drop)
template <int SKEW, int TRANS>
__launch_bounds__(256, 1)   // (256,w) empirically caps VGPR at 256/w (R6/R7/R9) — keep w=1
__global__ void gemm128(const bf16* __restrict__ A, const bf16* __restrict__ B,
                        bf16* __restrict__ C, int N, int K,
                        long aStride, long bStride, long cStride, int ldct)
{
    __shared__ bf16 smem[16384];          // A: [0,8192), B: [8192,16384)
    bf16* Als = smem;
    bf16* Bls = smem + 8192;

    int tid  = threadIdx.x;
    int lane = tid & 63;
    int wid  = tid >> 6;
    int l15  = lane & 15;
    int quad = lane >> 4;
    int nb = N >> 7;
    int gx = blockIdx.x % nb;
    int gy = blockIdx.x / nb;

    const bf16* Ab = A + (size_t)blockIdx.y * aStride + (size_t)gy * 128 * K;
    const bf16* Bb = B + (size_t)blockIdx.y * bStride + (size_t)gx * 128 * K;

    const bf16* gsrc = (wid < 2) ? Ab : Bb;
    bf16* ldst = (wid < 2) ? Als : Bls;
    int ibase = (wid & 1) * 8;            // 8 insts per wave, 16 per matrix
    int rl = lane >> 3;                   // row within 8-row inst
    int sl = lane & 7;                    // slot

    f32x4 acc[4][4];
    #pragma unroll
    for (int i = 0; i < 4; ++i)
        #pragma unroll
        for (int j = 0; j < 4; ++j) acc[i][j] = 0;

    for (int k0 = 0; k0 < K; k0 += 64) {
        #pragma unroll
        for (int u = 0; u < 8; ++u) {
            int inst = ibase + u;
            int row  = inst * 8 + rl;
            int c    = (sl - row) & 7;
            async_ld16(gsrc + (size_t)row * K + k0 + c * 8, ldst + inst * 512);
        }
        __syncthreads();                  // staging complete (vmcnt drain)
        #pragma unroll
        for (int ks = 0; ks < 2; ++ks) {
            bf16x8 fA[4], fB[4];
            #pragma unroll
            for (int rt = 0; rt < 4; ++rt) {
                int row = (wid & 1) * 64 + rt * 16 + l15;
                int s   = (ks * 4 + quad + row) & 7;
                fA[rt] = *(const bf16x8*)&Als[row * 64 + s * 8];
            }
            #pragma unroll
            for (int ct = 0; ct < 4; ++ct) {
                int col = (wid >> 1) * 64 + ct * 16 + l15;
                int s   = (ks * 4 + quad + col) & 7;
                fB[ct] = *(const bf16x8*)&Bls[col * 64 + s * 8];
            }
            #pragma unroll
            for (int rt = 0; rt < 4; ++rt)
                #pragma unroll
                for (int ct = 0; ct < 4; ++ct)
                    acc[rt][ct] = __builtin_amdgcn_mfma_f32_16x16x32_bf16(
                                      fA[rt], fB[ct], acc[rt][ct], 0, 0, 0);
        }
        __syncthreads();                  // LDS reuse guard
    }

    bf16* Cb = C + (size_t)blockIdx.y * cStride;
    int m0 = gy * 128 + (wid & 1) * 64;
    int n0 = gx * 128 + (wid >> 1) * 64;
    if (TRANS) {
        // stage C^T tile [n][m] into the (now-free) 32KB smem, swizzled slots
        #pragma unroll
        for (int rt = 0; rt < 4; ++rt)
            #pragma unroll
            for (int ct = 0; ct < 4; ++ct) {
                int nl = (wid >> 1) * 64 + ct * 16 + l15;
                int ml = (wid & 1) * 64 + rt * 16 + quad * 4;
                int slot = ((ml >> 3) + nl) & 15;
                bf16x4 pk;
                #pragma unroll
                for (int r = 0; r < 4; ++r) pk[r] = (bf16)acc[rt][ct][r];
                *(bf16x4*)&smem[nl * 128 + slot * 8 + (ml & 7)] = pk;
            }
        __syncthreads();
        int n = tid >> 1, mh = tid & 1;
        bf16* dst = Cb + (size_t)(gx * 128 + n) * ldct + gy * 128 + mh * 64;
        #pragma unroll
        for (int c8 = 0; c8 < 8; ++c8) {
            int chunk = mh * 8 + c8;
            int slot = (chunk + n) & 15;
            *(bf16x8*)(dst + c8 * 8) = *(const bf16x8*)&smem[n * 128 + slot * 8];
        }
    } else if (!SKEW) {
        #pragma unroll
        for (int rt = 0; rt < 4; ++rt)
            #pragma unroll
            for (int ct = 0; ct < 4; ++ct)
                #pragma unroll
                for (int r = 0; r < 4; ++r) {
                    int m = m0 + rt * 16 + quad * 4 + r;
                    int n = n0 + ct * 16 + l15;
                    Cb[(size_t)m * N + n] = (bf16)acc[rt][ct][r];
                }
    } else {
        #pragma unroll
        for (int rt = 0; rt < 4; ++rt)
            #pragma unroll
            for (int ct = 0; ct < 4; ++ct)
                #pragma unroll
                for (int r = 0; r < 4; ++r) {
                    int row = m0 + rt * 16 + quad * 4 + r;
                    int c   = n0 + ct * 16 + l15;
                    bool lower = (c >= LL - 1 - row);
                    int dr = lower ? row : row - 1;
                    int dc = lower ? c - (LL - 1 - row) : c + row + 1;
                    if (lower || row >= 1)
                        Cb[(size_t)dr * LL + dc] = (bf16)acc[rt][ct][r];
                }
    }
}

// Fused attention: XCD-pinned (blockIdx%8 -> (b,dh)); K staged to LDS async;
// V direct global->VGPR (XCD-L2-resident); 3 barriers/iter.
// (256,1): R9's (256,3) capped VGPR at 84 -> V-frag spill (+11MB scratch writes).
// All accO loops fully unrolled (R3: dynamic index => scratch spill).
__launch_bounds__(256, 1)
__global__ void attn_kernel(const bf16* __restrict__ Qw, const bf16* __restrict__ Kw,
                            const bf16* __restrict__ Vt, const bf16* __restrict__ Srel,
                            float* __restrict__ out)
{
    __shared__ bf16  Klds[64 * 256];
    __shared__ float Ss[32][68];
    __shared__ bf16  Ps[32][72];
    __shared__ float mSt[32], lSt[32], aSt[32];

    int tid  = threadIdx.x;
    int lane = tid & 63;
    int wid  = tid >> 6;
    int l15  = lane & 15;
    int quad = lane >> 4;

    int xcd = blockIdx.x & 7;
    int b   = xcd >> 1;
    int dh  = xcd & 1;
    int i0  = (blockIdx.x >> 3) * 32;

    const bf16* Qb = Qw + (size_t)b * LL * DKK;
    const bf16* Kb = Kw + (size_t)b * LL * DKK;
    const bf16* Sb = Srel + (size_t)b * LL * LL;
    const bf16* Vb = Vt + (size_t)(dh * 256) * (BB * LL) + (size_t)b * LL;

    bf16x8 Qreg[2][8];
    #pragma unroll
    for (int rt = 0; rt < 2; ++rt)
        #pragma unroll
        for (int ks = 0; ks < 8; ++ks)
            Qreg[rt][ks] = *(const bf16x8*)(Qb + (size_t)(i0 + rt * 16 + l15) * DKK
                                            + ks * 32 + quad * 8);

    if (tid < 32) { mSt[tid] = -1e30f; lSt[tid] = 0.f; }

    f32x4 accO[2][4];
    #pragma unroll
    for (int rt = 0; rt < 2; ++rt)
        #pragma unroll
        for (int nt = 0; nt < 4; ++nt) accO[rt][nt] = 0;

    for (int j0 = 0; j0 < LL; j0 += 64) {
        #pragma unroll
        for (int u = 0; u < 8; ++u) {
            int inst = wid * 8 + u;
            int s = inst * 64 + lane;
            int j = s >> 5, cp = lane & 31;
            int c = (cp - j) & 31;
            async_ld16(Kb + (size_t)(j0 + j) * DKK + c * 8, Klds + inst * 512);
        }
        bf16x8 vF0[4], vF1[4];
        #pragma unroll
        for (int nt = 0; nt < 4; ++nt) {
            const bf16* vp = Vb + (size_t)(wid * 64 + nt * 16 + l15) * (BB * LL)
                           + j0 + quad * 8;
            vF0[nt] = *(const bf16x8*)(vp);
            vF1[nt] = *(const bf16x8*)(vp + 32);
        }
        __syncthreads();                                    // b1
        {
            f32x4 s0 = 0, s1 = 0;
            int jrow = wid * 16 + l15;
            #pragma unroll
            for (int ks = 0; ks < 8; ++ks) {
                int c = ks * 4 + quad;
                int cp = (c + jrow) & 31;
                bf16x8 kf = *(const bf16x8*)&Klds[jrow * 256 + cp * 8];
                s0 = __builtin_amdgcn_mfma_f32_16x16x32_bf16(Qreg[0][ks], kf, s0, 0, 0, 0);
                s1 = __builtin_amdgcn_mfma_f32_16x16x32_bf16(Qreg[1][ks], kf, s1, 0, 0, 0);
            }
            #pragma unroll
            for (int r = 0; r < 4; ++r) {
                Ss[quad * 4 + r][wid * 16 + l15]      = s0[r];
                Ss[16 + quad * 4 + r][wid * 16 + l15] = s1[r];
            }
        }
        __syncthreads();                                    // b2
        {
            int r = tid >> 3, sg = tid & 7;
            int i = i0 + r;
            bf16x8 s8 = *(const bf16x8*)(Sb + (size_t)i * LL + j0 + sg * 8);
            float v[8];
            #pragma unroll
            for (int c = 0; c < 8; ++c) {
                float sr = (j0 + sg * 8 + c == i + 1) ? 0.f : (float)s8[c];
                v[c] = (Ss[r][sg * 8 + c] + sr) * 0.0625f;
            }
            float tmax = v[0];
            #pragma unroll
            for (int c = 1; c < 8; ++c) tmax = fmaxf(tmax, v[c]);
            tmax = fmaxf(tmax, __shfl_xor(tmax, 1));
            tmax = fmaxf(tmax, __shfl_xor(tmax, 2));
            tmax = fmaxf(tmax, __shfl_xor(tmax, 4));
            float mOld = mSt[r], lOld = lSt[r];
            float mNew = fmaxf(mOld, tmax);
            float alpha = __expf(mOld - mNew);
            float ps = 0.f;
            bf16x8 pv;
            #pragma unroll
            for (int c = 0; c < 8; ++c) {
                float p = __expf(v[c] - mNew);
                ps += p;
                pv[c] = (bf16)p;
            }
            ps += __shfl_xor(ps, 1);
            ps += __shfl_xor(ps, 2);
            ps += __shfl_xor(ps, 4);
            *(bf16x8*)&Ps[r][sg * 8] = pv;
            if (sg == 0) { mSt[r] = mNew; lSt[r] = alpha * lOld + ps; aSt[r] = alpha; }
        }
        __syncthreads();                                    // b3
        {
            bf16x8 aF[2][2];
            #pragma unroll
            for (int rt = 0; rt < 2; ++rt)
                #pragma unroll
                for (int kk = 0; kk < 2; ++kk)
                    aF[rt][kk] = *(const bf16x8*)&Ps[rt * 16 + l15][kk * 32 + quad * 8];
            float ar[2][4];
            #pragma unroll
            for (int rt = 0; rt < 2; ++rt)
                #pragma unroll
                for (int r = 0; r < 4; ++r) ar[rt][r] = aSt[rt * 16 + quad * 4 + r];
            #pragma unroll
            for (int nt = 0; nt < 4; ++nt) {
                #pragma unroll
                for (int rt = 0; rt < 2; ++rt) {
                    f32x4 o = accO[rt][nt];
                    o[0] *= ar[rt][0]; o[1] *= ar[rt][1];
                    o[2] *= ar[rt][2]; o[3] *= ar[rt][3];
                    o = __builtin_amdgcn_mfma_f32_16x16x32_bf16(aF[rt][0], vF0[nt], o, 0, 0, 0);
                    o = __builtin_amdgcn_mfma_f32_16x16x32_bf16(aF[rt][1], vF1[nt], o, 0, 0, 0);
                    accO[rt][nt] = o;
                }
            }
        }
        // (no b4: next-iter Klds writes WAR-protected by b2+b3; Ps by b1'+b2')
    }
    float lr[2][4];
    #pragma unroll
    for (int rt = 0; rt < 2; ++rt)
        #pragma unroll
        for (int r = 0; r < 4; ++r) lr[rt][r] = 1.f / lSt[rt * 16 + quad * 4 + r];
    #pragma unroll
    for (int rt = 0; rt < 2; ++rt)
        #pragma unroll
        for (int nt = 0; nt < 4; ++nt)
            #pragma unroll
            for (int r = 0; r < 4; ++r) {
                int i = i0 + rt * 16 + quad * 4 + r;
                int d = dh * 256 + wid * 64 + nt * 16 + l15;
                out[((size_t)b * LL + i) * DD + d] = accO[rt][nt][r] * lr[rt][r];
            }
}

extern "C" void kernel_launch(void* const* d_in, const int* in_sizes, int n_in,
                              void* d_out, int out_size, void* d_ws, size_t ws_size,
                              hipStream_t stream) {
    const float* inQ = (const float*)d_in[0];
    const float* inK = (const float*)d_in[1];
    const float* inV = (const float*)d_in[2];
    const float* Wq  = (const float*)d_in[3];
    const float* Wk  = (const float*)d_in[4];
    const float* Wv  = (const float*)d_in[5];
    const float* E   = (const float*)d_in[6];
    float* out = (float*)d_out;

    char* ws = (char*)d_ws;
    bf16* Qw   = (bf16*)(ws);                         // 4 MB [B*L][DK]
    bf16* Kw   = (bf16*)(ws + ((size_t)4  << 20));    // 4 MB [B*L][DK]  (= Qw + 2M elems)
    bf16* Vt   = (bf16*)(ws + ((size_t)8  << 20));    // 8 MB [D][B*L]
    bf16* SrelW= (bf16*)(ws + ((size_t)16 << 20));    // 32 MB [B,L,L] skewed
    // transients inside Srel region (dead before Srel gemm writes):
    bf16* Xq   = (bf16*)(ws + ((size_t)16 << 20));    // 8 MB (= Xq + 4M elems -> Xk)
    bf16* Xk   = (bf16*)(ws + ((size_t)24 << 20));    // 8 MB
    bf16* Xv   = (bf16*)(ws + ((size_t)32 << 20));    // 8 MB
    bf16* WqT  = (bf16*)(ws + ((size_t)48 << 20));              // [DK][D]
    bf16* WkT  = (bf16*)(ws + ((size_t)48 << 20) + 262144);     // [DK][D] (= WqT + 128K elems)
    bf16* WvT  = (bf16*)(ws + ((size_t)48 << 20) + 524288);     // [D][D]
    bf16* Eb   = (bf16*)(ws + ((size_t)49 << 20));              // [L][DK]

    {
        const int NV = (BB * LL * DD) / 4, NE = (LL * DKK) / 4;
        conv_all<<<(3 * NV + NE + 255) / 256, 256, 0, stream>>>(
            inQ, inK, inV, E, Xq, Xk, Xv, Eb);
    }
    trans_all<<<(2 * DD * DKK + DD * DD + 255) / 256, 256, 0, stream>>>(
        Wq, Wk, Wv, WqT, WkT, WvT);

    // Q and K projections fused: y=0 -> Q, y=1 -> K.
    gemm128<0, 0><<<dim3(2 * 64, 2), 256, 0, stream>>>(
        Xq, WqT, Qw, DKK, DD,
        (long)4 * 1024 * 1024, (long)131072, (long)2 * 1024 * 1024, 0);
    // V projection fused with transpose: Vt[d][B*L] directly.
    gemm128<0, 1><<<dim3(4 * 64, 1), 256, 0, stream>>>(
        Xv, WvT, Vt, DD, DD, 0, 0, 0, BB * LL);
    // Srel (skewed) = skew(Q·E^T): per-batch M=N=2048 K=256.
    gemm128<1, 0><<<dim3(16 * 16, BB), 256, 0, stream>>>(
        Qw, Eb, SrelW, LL, DKK, (long)LL * DKK, 0, (long)LL * LL, 0);
    attn_kernel<<<dim3(BB * 64 * 2), 256, 0, stream>>>(Qw, Kw, Vt, SrelW, out);
}